// Round 17
// baseline (622.878 us; speedup 1.0000x reference)
//
#include <hip/hip_runtime.h>
#include <hip/hip_fp16.h>

#define N_NODES 50000
#define M_EDGES 10000
#define NNZ_TOT 400000
#define DF      128
#define HID     256
#define NOUT    40

#define VBLK 196            // 196*256 = 50176 >= 50000
#define EBLK 40             // 40*256  = 10240 >= 10000
#define SBLK (VBLK + EBLK)  // 236 scan blocks

typedef _Float16 fp16x8 __attribute__((ext_vector_type(8)));
typedef float    f32x4  __attribute__((ext_vector_type(4)));
typedef float    f32x4v __attribute__((ext_vector_type(4)));   // native vec for nontemporal builtins

// ---------------------------------------------------------------- CSR build
__global__ __launch_bounds__(256) void count_kernel(const int* __restrict__ V, const int* __restrict__ E,
                                                    int* __restrict__ cntV, int* __restrict__ cntE) {
  int i = blockIdx.x * 256 + threadIdx.x;
  if (i < NNZ_TOT) {
    int v = V[i]; v = (v < 0) ? 0 : (v >= N_NODES ? N_NODES - 1 : v);
    int e = E[i]; e = (e < 0) ? 0 : (e >= M_EDGES ? M_EDGES - 1 : e);
    atomicAdd(&cntV[v], 1);
    atomicAdd(&cntE[e], 1);
  }
}

// ---- multi-block scan, both segments in one grid; also emits invDE/invSqrtD ----
__global__ __launch_bounds__(256) void scan1_kernel(const int* __restrict__ cntV, const int* __restrict__ cntE,
                                                    int* __restrict__ rowptrV, int* __restrict__ rowptrE,
                                                    int* __restrict__ blockSums,
                                                    float* __restrict__ invSqrtD,
                                                    float* __restrict__ invDE) {
  __shared__ int sm[256];
  const int b = blockIdx.x;
  const int tid = threadIdx.x;
  const bool isV = b < VBLK;
  const int n = isV ? N_NODES : M_EDGES;
  const int i = (isV ? b : b - VBLK) * 256 + tid;
  const int* cnt = isV ? cntV : cntE;
  int x = (i < n) ? cnt[i] : 0;
  if (i < n) {
    if (isV) invSqrtD[i] = 1.0f / sqrtf((float)x);
    else     invDE[i] = 1.0f / (float)x;
  }
  sm[tid] = x;
  __syncthreads();
#pragma unroll
  for (int off = 1; off < 256; off <<= 1) {
    int t = (tid >= off) ? sm[tid - off] : 0;
    __syncthreads();
    sm[tid] += t;
    __syncthreads();
  }
  int inc = sm[tid];
  int* rp = isV ? rowptrV : rowptrE;
  if (i < n) rp[i] = inc - x;
  if (tid == 255) blockSums[b] = inc;
}

__global__ __launch_bounds__(256) void scan2_kernel(int* __restrict__ blockSums) {
  __shared__ int sm[256];
  const int tid = threadIdx.x;
  int x = (tid < SBLK) ? blockSums[tid] : 0;
  sm[tid] = x;
  __syncthreads();
  const int segStart = (tid < VBLK) ? 0 : VBLK;
#pragma unroll
  for (int off = 1; off < 256; off <<= 1) {
    int t = (tid >= off && (tid - off) >= segStart) ? sm[tid - off] : 0;
    __syncthreads();
    sm[tid] += t;
    __syncthreads();
  }
  if (tid < SBLK) blockSums[tid] = sm[tid] - x;
}

__global__ __launch_bounds__(256) void scan3_kernel(int* __restrict__ cntV, int* __restrict__ cntE,
                                                    int* __restrict__ rowptrV, int* __restrict__ rowptrE,
                                                    const int* __restrict__ blockSums) {
  const int b = blockIdx.x;
  const int tid = threadIdx.x;
  const bool isV = b < VBLK;
  const int n = isV ? N_NODES : M_EDGES;
  const int i = (isV ? b : b - VBLK) * 256 + tid;
  int* rp = isV ? rowptrV : rowptrE;
  int* cur = isV ? cntV : cntE;
  if (i < n) {
    int val = rp[i] + blockSums[b];
    rp[i] = val;
    cur[i] = val;
  }
  if (b == 0 && tid == 0) { rowptrV[N_NODES] = NNZ_TOT; rowptrE[M_EDGES] = NNZ_TOT; }
}

__global__ __launch_bounds__(256) void fill_kernel(const int* __restrict__ V, const int* __restrict__ E,
                                                   int* __restrict__ curV, int* __restrict__ curE,
                                                   int* __restrict__ colE, int* __restrict__ colV) {
  int i = blockIdx.x * 256 + threadIdx.x;
  if (i < NNZ_TOT) {
    int v = V[i]; v = (v < 0) ? 0 : (v >= N_NODES ? N_NODES - 1 : v);
    int e = E[i]; e = (e < 0) ? 0 : (e >= M_EDGES ? M_EDGES - 1 : e);
    int p = atomicAdd(&curV[v], 1);
    colE[p] = e;
    int q = atomicAdd(&curE[e], 1);
    colV[q] = v;
  }
}

__global__ __launch_bounds__(256) void node_stats_kernel(const int* __restrict__ rowptrV,
                                                         const int* __restrict__ colE,
                                                         const float* __restrict__ invDE,
                                                         float* __restrict__ rv) {
  int v = blockIdx.x * 256 + threadIdx.x;
  if (v < N_NODES) {
    int b = rowptrV[v], e = rowptrV[v + 1];
    float r = 0.0f;
    for (int j = b; j < e; ++j) r += invDE[colE[j]];
    rv[v] = r;
  }
}

// one-time merged weight convert: W1 -> W1t [256][128] fp16; W2 -> W2t [48][256] fp16 (zero-pad 40..47)
__global__ __launch_bounds__(256) void wcvt_kernel(const float* __restrict__ W1, const float* __restrict__ W2,
                                                   __half* __restrict__ W1t, __half* __restrict__ W2t) {
  int i = blockIdx.x * 256 + threadIdx.x;
  if (i < DF * HID) {
    int k = i >> 8, n = i & 255;
    W1t[n * DF + k] = __float2half(W1[i]);
  } else {
    int j = i - DF * HID;                    // 0 .. 48*HID-1
    if (j < 48 * HID) {
      int n = j >> 8, k = j & 255;
      W2t[n * HID + k] = (n < NOUT) ? __float2half(W2[k * NOUT + n]) : __float2half(0.f);
    }
  }
}

// ------------------------------------------------------------- phi0: Bh0 = fp16(X*isd), Xh = fp16(X), phi partial
__global__ __launch_bounds__(256) void phi0_kernel(const float* __restrict__ X,
                                                   const float* __restrict__ invSqrtD,
                                                   const float* __restrict__ rv,
                                                   __half2* __restrict__ Bh,
                                                   __half2* __restrict__ Xh,
                                                   float* __restrict__ slot0) {
  __shared__ float red[4];
  int w = threadIdx.x >> 6;
  int v = (blockIdx.x << 2) + w;
  v = __builtin_amdgcn_readfirstlane(v);
  int lane = threadIdx.x & 63;
  float isd = invSqrtD[v];
  float2 xv = *(const float2*)(X + (size_t)v * DF + lane * 2);
  float bx = xv.x * isd, by = xv.y * isd;
  Bh[(size_t)v * 64 + lane] = __floats2half2_rn(bx, by);
  Xh[(size_t)v * 64 + lane] = __floats2half2_rn(xv.x, xv.y);
  float q = bx * bx + by * by;
#pragma unroll
  for (int off = 32; off > 0; off >>= 1) q += __shfl_down(q, off, 64);
  if (lane == 0) red[w] = q * rv[v];
  __syncthreads();
  if (threadIdx.x == 0)
    atomicAdd(&slot0[blockIdx.x & 63], red[0] + red[1] + red[2] + red[3]);
}

// ------------------------------------------------------------- V2E pass (one edge per wave)
// batches of 8 gathers, each PREDICATED on row validity (plain loads: Bh rows have no
// within-XCD reuse, L3-bound regardless — keep them cacheable for the little reuse there is).
__global__ __launch_bounds__(256) void v2e_kernel(const __half2* __restrict__ Bh, __half2* __restrict__ Peh,
                                                  const int* __restrict__ rowptrE,
                                                  const int* __restrict__ colV,
                                                  const float* __restrict__ invDE) {
  const int tid = threadIdx.x;
  const int lane = tid & 63;
  const int grp = lane >> 4;
  const int sub = lane & 15;
  const int e = blockIdx.x * 4 + (tid >> 6);   // grid 2500*4 = 10000 exact
  const int beg = rowptrE[e], end = rowptrE[e + 1];
  const int cnt = end - beg;

  float acc[8];
#pragma unroll
  for (int i = 0; i < 8; ++i) acc[i] = 0.f;
  const char* Bb = (const char*)Bh;

  for (int c0 = 0; c0 < cnt; c0 += 64) {
    int li = c0 + lane;
    int idx = colV[beg + (li < cnt ? li : cnt - 1)];
#pragma unroll 1
    for (int half = 0; half < 2; ++half) {
      int base0 = c0 + half * 32;
      if (base0 >= cnt) break;               // wave-uniform
      float4 r[8];
      bool ok[8];
#pragma unroll
      for (int u = 0; u < 8; ++u) {          // issue 8 predicated gathers back-to-back
        ok[u] = (base0 + u * 4 + grp) < cnt;
        int m = __shfl(idx, (half * 8 + u) * 4 + grp, 64);
        if (ok[u]) r[u] = *(const float4*)(Bb + ((size_t)m << 8) + (sub << 4));
      }
#pragma unroll
      for (int u = 0; u < 8; ++u) {
        if (ok[u]) {
          const __half2* h = (const __half2*)&r[u];
          float2 a0 = __half22float2(h[0]);
          float2 a1 = __half22float2(h[1]);
          float2 a2 = __half22float2(h[2]);
          float2 a3 = __half22float2(h[3]);
          acc[0] += a0.x * a0.x; acc[1] += a0.y * a0.y;
          acc[2] += a1.x * a1.x; acc[3] += a1.y * a1.y;
          acc[4] += a2.x * a2.x; acc[5] += a2.y * a2.y;
          acc[6] += a3.x * a3.x; acc[7] += a3.y * a3.y;
        }
      }
    }
  }
#pragma unroll
  for (int i = 0; i < 8; ++i) {
    acc[i] += __shfl_xor(acc[i], 16, 64);
    acc[i] += __shfl_xor(acc[i], 32, 64);
  }
  if (grp == 0) {
    float de = invDE[e];
    __half2 o[4];
#pragma unroll
    for (int i = 0; i < 4; ++i)
      o[i] = __floats2half2_rn(sqrtf(acc[2 * i] * de), sqrtf(acc[2 * i + 1] * de));
    *(float4*)((char*)Peh + ((size_t)e << 8) + (sub << 4)) = *(const float4*)o;
  }
}

// ------------------------------------------------------------- E2V (4 nodes per wave) + G + phi
// Pe gathers stay CACHEABLE (Peh 2.56MB fits per-XCD L2, ~5 refs/row/XCD);
// Xh read + Bh write are single-touch STREAMS -> nontemporal, so they don't evict Pe from L2.
__global__ __launch_bounds__(256) void e2v_kernel(const __half2* __restrict__ Peh,
                                                  const __half2* __restrict__ Xh,
                                                  __half2* __restrict__ Bh,
                                                  const int* __restrict__ rowptrV,
                                                  const int* __restrict__ colE,
                                                  const float* __restrict__ invSqrtD,
                                                  const float* __restrict__ rv,
                                                  const float* __restrict__ slot0,
                                                  const float* __restrict__ slotPrev,
                                                  float* __restrict__ slotOut,
                                                  int isLast) {
  __shared__ float red[16];
  const int tid = threadIdx.x;
  const int lane = tid & 63;
  const int grp = lane >> 4;
  const int sub = lane & 15;
  const int wv = tid >> 6;
  const int v = blockIdx.x * 16 + wv * 4 + grp;   // grid 3125*16 = 50000 exact

  float p0 = slot0[lane];
  float pp = slotPrev[lane];
#pragma unroll
  for (int off = 32; off > 0; off >>= 1) {
    p0 += __shfl_xor(p0, off, 64);
    pp += __shfl_xor(pp, off, 64);
  }
  float s0 = 1.0f / (2.0f * sqrtf(p0));
  float sp = 1.0f / (2.0f * sqrtf(pp));

  const int beg = rowptrV[v], end = rowptrV[v + 1];
  const int cnt = end - beg;
  int cmax = cnt;
  cmax = max(cmax, __shfl_xor(cmax, 16, 64));
  cmax = max(cmax, __shfl_xor(cmax, 32, 64));

  float acc[8];
#pragma unroll
  for (int i = 0; i < 8; ++i) acc[i] = 0.f;
  const char* Pb = (const char*)Peh;

  for (int c0 = 0; c0 < cmax; c0 += 16) {
    int li = c0 + sub;
    int eidx = colE[beg + (li < cnt ? li : cnt - 1)];
    bool second = (c0 + 8 < cmax);            // wave-uniform
    float4 r[8], r2[8];
    bool ok[8], ok2[8];
#pragma unroll
    for (int u = 0; u < 8; ++u) {             // first 8 predicated gathers
      ok[u] = (c0 + u) < cnt;
      int m = __shfl(eidx, (grp << 4) | u, 64);
      if (ok[u]) r[u] = *(const float4*)(Pb + ((size_t)m << 8) + (sub << 4));
    }
    if (second) {
#pragma unroll
      for (int u = 0; u < 8; ++u) {           // next 8 (same index load)
        ok2[u] = (c0 + 8 + u) < cnt;
        int m = __shfl(eidx, (grp << 4) | (8 + u), 64);
        if (ok2[u]) r2[u] = *(const float4*)(Pb + ((size_t)m << 8) + (sub << 4));
      }
    }
#pragma unroll
    for (int u = 0; u < 8; ++u) {
      if (ok[u]) {
        const __half2* h = (const __half2*)&r[u];
        float2 a0 = __half22float2(h[0]);
        float2 a1 = __half22float2(h[1]);
        float2 a2 = __half22float2(h[2]);
        float2 a3 = __half22float2(h[3]);
        acc[0] += a0.x; acc[1] += a0.y;
        acc[2] += a1.x; acc[3] += a1.y;
        acc[4] += a2.x; acc[5] += a2.y;
        acc[6] += a3.x; acc[7] += a3.y;
      }
    }
    if (second) {
#pragma unroll
      for (int u = 0; u < 8; ++u) {
        if (ok2[u]) {
          const __half2* h = (const __half2*)&r2[u];
          float2 a0 = __half22float2(h[0]);
          float2 a1 = __half22float2(h[1]);
          float2 a2 = __half22float2(h[2]);
          float2 a3 = __half22float2(h[3]);
          acc[0] += a0.x; acc[1] += a0.y;
          acc[2] += a1.x; acc[3] += a1.y;
          acc[4] += a2.x; acc[5] += a2.y;
          acc[6] += a3.x; acc[7] += a3.y;
        }
      }
    }
  }

  float isd = invSqrtD[v];
  float c1 = 0.9f * sp * isd;
  float c0w = 0.1f * s0;
  f32x4v xr = __builtin_nontemporal_load((const f32x4v*)((const char*)Xh + ((size_t)v << 8) + (sub << 4)));
  const __half2* xh = (const __half2*)&xr;
  float g[8];
#pragma unroll
  for (int i = 0; i < 4; ++i) {
    float2 xv = __half22float2(xh[i]);
    g[2 * i]     = c1 * acc[2 * i]     + c0w * xv.x;
    g[2 * i + 1] = c1 * acc[2 * i + 1] + c0w * xv.y;
  }
  float q = 0.f;
  __half2 o[4];
#pragma unroll
  for (int i = 0; i < 4; ++i) {
    float b0 = g[2 * i] * isd, b1 = g[2 * i + 1] * isd;
    q += b0 * b0 + b1 * b1;
    o[i] = isLast ? __floats2half2_rn(g[2 * i], g[2 * i + 1])
                  : __floats2half2_rn(b0, b1);
  }
  __builtin_nontemporal_store(*(const f32x4v*)o, (f32x4v*)((char*)Bh + ((size_t)v << 8) + (sub << 4)));

#pragma unroll
  for (int off = 8; off > 0; off >>= 1) q += __shfl_xor(q, off, 64);
  if (sub == 0) red[wv * 4 + grp] = q * rv[v];
  __syncthreads();
  if (tid == 0) {
    float t = 0.f;
#pragma unroll
    for (int i = 0; i < 16; ++i) t += red[i];
    atomicAdd(&slotOut[blockIdx.x & 63], t);
  }
}

// ------------------------------------------------------------- fused decoder (MFMA both GEMMs)
// 256 threads = 4 waves, 64 nodes/block. Wave w owns nodes [w*16, +16) x ALL 256 hid:
// LN fully in-wave (no cross-wave combine); W1t/W2t L2 traffic halved vs 32-node blocks.
__global__ __launch_bounds__(256) void decoder_kernel(const __half2* __restrict__ Gh,
                                                      const __half* __restrict__ W1t,
                                                      const __half* __restrict__ W2t,
                                                      const float* __restrict__ slot10,
                                                      const float* __restrict__ b1,
                                                      const float* __restrict__ gam, const float* __restrict__ bet,
                                                      const float* __restrict__ b2,
                                                      float* __restrict__ out) {
  __shared__ __half h16[64 * 264];         // 33,792 B
  const int tid = threadIdx.x;
  const int lane = tid & 63;
  const int w = tid >> 6;                  // wave 0..3
  const int quad = lane >> 4;
  const int col = lane & 15;
  const int node0 = blockIdx.x * 64;
  const int m0 = w * 16;                   // this wave's 16-node tile

  float ps = slot10[lane];
#pragma unroll
  for (int off = 32; off > 0; off >>= 1) ps += __shfl_xor(ps, off, 64);
  const float s = 1.0f / (2.0f * sqrtf(ps));   // 1/phi(G10)

  f32x4 acc[16];
#pragma unroll
  for (int t = 0; t < 16; ++t) acc[t] = (f32x4){0.f, 0.f, 0.f, 0.f};

  int an = node0 + m0 + col;
  if (an > N_NODES - 1) an = N_NODES - 1;
  const char* Gb = (const char*)Gh;
  const char* Wb = (const char*)W1t;

#pragma unroll
  for (int kb = 0; kb < 4; ++kb) {
    fp16x8 af = *(const fp16x8*)(Gb + (size_t)an * 256 + kb * 64 + quad * 16);
#pragma unroll
    for (int t = 0; t < 16; ++t) {
      int n = t * 16 + col;
      fp16x8 bf = *(const fp16x8*)(Wb + (size_t)n * 256 + kb * 64 + quad * 16);
      acc[t] = __builtin_amdgcn_mfma_f32_16x16x32_f16(af, bf, acc[t], 0, 0, 0);
    }
  }

  // h = s*acc + b1 (stored back into acc), LN stats fully in-wave
  float s1[4] = {0.f, 0.f, 0.f, 0.f}, s2[4] = {0.f, 0.f, 0.f, 0.f};
#pragma unroll
  for (int t = 0; t < 16; ++t) {
    float bb = b1[t * 16 + col];
#pragma unroll
    for (int r = 0; r < 4; ++r) {
      float h = s * acc[t][r] + bb;
      acc[t][r] = h;
      s1[r] += h;
      s2[r] += h * h;
    }
  }
#pragma unroll
  for (int off = 8; off > 0; off >>= 1) {
#pragma unroll
    for (int r = 0; r < 4; ++r) {
      s1[r] += __shfl_xor(s1[r], off, 64);
      s2[r] += __shfl_xor(s2[r], off, 64);
    }
  }
  float mu[4], rs[4];
#pragma unroll
  for (int r = 0; r < 4; ++r) {
    float m = s1[r] * (1.0f / 256.0f);
    float var = s2[r] * (1.0f / 256.0f) - m * m;
    mu[r] = m;
    rs[r] = rsqrtf(var + 1e-5f);
  }
  // LN + ReLU + dump h to LDS fp16
#pragma unroll
  for (int t = 0; t < 16; ++t) {
    int hid = t * 16 + col;
    float ga = gam[hid], be = bet[hid];
#pragma unroll
    for (int r = 0; r < 4; ++r) {
      float h = fmaxf(0.0f, (acc[t][r] - mu[r]) * rs[r] * ga + be);
      h16[(m0 + quad * 4 + r) * 264 + hid] = __float2half(h);
    }
  }
  __syncthreads();

  // GEMM2: wave w -> its own 16 nodes x 48 outs, K=256
  {
    f32x4 c[3];
#pragma unroll
    for (int nt = 0; nt < 3; ++nt) c[nt] = (f32x4){0.f, 0.f, 0.f, 0.f};
#pragma unroll
    for (int kb = 0; kb < 8; ++kb) {
      fp16x8 af = *(const fp16x8*)&h16[(m0 + col) * 264 + kb * 32 + quad * 8];
#pragma unroll
      for (int nt = 0; nt < 3; ++nt) {
        fp16x8 bf = *(const fp16x8*)(W2t + (nt * 16 + col) * HID + kb * 32 + quad * 8);
        c[nt] = __builtin_amdgcn_mfma_f32_16x16x32_f16(af, bf, c[nt], 0, 0, 0);
      }
    }
#pragma unroll
    for (int nt = 0; nt < 3; ++nt) {
      int oc = nt * 16 + col;
      if (oc < NOUT) {
        float bb = b2[oc];
#pragma unroll
        for (int r = 0; r < 4; ++r) {
          int node = node0 + m0 + quad * 4 + r;
          if (node < N_NODES) out[(size_t)node * NOUT + oc] = c[nt][r] + bb;
        }
      }
    }
  }
}

// ---------------------------------------------------------------- launch
extern "C" void kernel_launch(void* const* d_in, const int* in_sizes, int n_in,
                              void* d_out, int out_size, void* d_ws, size_t ws_size,
                              hipStream_t stream) {
  (void)in_sizes; (void)n_in; (void)out_size; (void)ws_size;
  const float* x = (const float*)d_in[0];
  const int* he = (const int*)d_in[1];
  const int* V = he;
  const int* E = he + NNZ_TOT;
  const float* W1 = (const float*)d_in[2];
  const float* b1 = (const float*)d_in[3];
  const float* gam = (const float*)d_in[4];
  const float* bet = (const float*)d_in[5];
  const float* W2 = (const float*)d_in[6];
  const float* b2 = (const float*)d_in[7];
  float* out = (float*)d_out;

  // Peh (2.56 MB fp16) lives in d_out (8 MB): dead before decoder (sole d_out writer) runs.
  __half2* Peh = (__half2*)d_out;

  char* p = (char*)d_ws;
  auto nextp = [&](size_t bytes) -> char* {
    char* r = p;
    p += (bytes + 255) & ~(size_t)255;
    return r;
  };
  int* cntV      = (int*)nextp((size_t)(N_NODES + M_EDGES) * 4 + 11 * 64 * 4);
  int* cntE      = cntV + N_NODES;
  float* phis    = (float*)(cntE + M_EDGES);     // [11][64] striped phi partials
  int* rowptrV   = (int*)nextp((size_t)(N_NODES + 1) * 4);
  int* rowptrE   = (int*)nextp((size_t)(M_EDGES + 1) * 4);
  int* blockSums = (int*)nextp((size_t)SBLK * 4);
  int* colE      = (int*)nextp((size_t)NNZ_TOT * 4);
  int* colV      = (int*)nextp((size_t)NNZ_TOT * 4);
  float* invSqrtD= (float*)nextp((size_t)N_NODES * 4);
  float* rv      = (float*)nextp((size_t)N_NODES * 4);
  float* invDE   = (float*)nextp((size_t)M_EDGES * 4);
  __half* W1t    = (__half*)nextp((size_t)DF * HID * 2);        // fp16 W1^T, 64 KB
  __half* W2t    = (__half*)nextp((size_t)48 * HID * 2);        // fp16 W2^T padded, 24.6 KB
  __half2* Bh    = (__half2*)nextp((size_t)N_NODES * DF * 2);   // fp16 iterate, 12.8 MB
  __half2* Xh    = (__half2*)nextp((size_t)N_NODES * DF * 2);   // fp16 anchor, 12.8 MB

  const int NBLK_NNZ = (NNZ_TOT + 255) / 256;

  hipMemsetAsync(cntV, 0, (size_t)(N_NODES + M_EDGES) * 4 + 11 * 64 * 4, stream);
  count_kernel<<<NBLK_NNZ, 256, 0, stream>>>(V, E, cntV, cntE);
  scan1_kernel<<<SBLK, 256, 0, stream>>>(cntV, cntE, rowptrV, rowptrE, blockSums, invSqrtD, invDE);
  scan2_kernel<<<1, 256, 0, stream>>>(blockSums);
  scan3_kernel<<<SBLK, 256, 0, stream>>>(cntV, cntE, rowptrV, rowptrE, blockSums);
  fill_kernel<<<NBLK_NNZ, 256, 0, stream>>>(V, E, cntV, cntE, colE, colV);
  node_stats_kernel<<<(N_NODES + 255) / 256, 256, 0, stream>>>(rowptrV, colE, invDE, rv);
  wcvt_kernel<<<(DF * HID + 48 * HID + 255) / 256, 256, 0, stream>>>(W1, W2, W1t, W2t);
  phi0_kernel<<<N_NODES / 4, 256, 0, stream>>>(x, invSqrtD, rv, Bh, Xh, phis);

  for (int k = 1; k <= 10; ++k) {
    v2e_kernel<<<M_EDGES / 4, 256, 0, stream>>>(Bh, Peh, rowptrE, colV, invDE);
    e2v_kernel<<<N_NODES / 16, 256, 0, stream>>>(Peh, Xh, Bh, rowptrV, colE, invSqrtD, rv,
                                                 phis, phis + (size_t)(k - 1) * 64,
                                                 phis + (size_t)k * 64, (k == 10) ? 1 : 0);
  }

  decoder_kernel<<<(N_NODES + 63) / 64, 256, 0, stream>>>(Bh, W1t, W2t, phis + 640,
                                                          b1, gam, bet, b2, out);
}

// Round 18
// 596.464 us; speedup vs baseline: 1.0443x; 1.0443x over previous
//
#include <hip/hip_runtime.h>
#include <hip/hip_fp16.h>

#define N_NODES 50000
#define M_EDGES 10000
#define NNZ_TOT 400000
#define DF      128
#define HID     256
#define NOUT    40

#define VBLK 196            // 196*256 = 50176 >= 50000
#define EBLK 40             // 40*256  = 10240 >= 10000
#define SBLK (VBLK + EBLK)  // 236 scan blocks

typedef _Float16 fp16x8 __attribute__((ext_vector_type(8)));
typedef float    f32x4  __attribute__((ext_vector_type(4)));

// ---------------------------------------------------------------- CSR build
__global__ __launch_bounds__(256) void count_kernel(const int* __restrict__ V, const int* __restrict__ E,
                                                    int* __restrict__ cntV, int* __restrict__ cntE) {
  int i = blockIdx.x * 256 + threadIdx.x;
  if (i < NNZ_TOT) {
    int v = V[i]; v = (v < 0) ? 0 : (v >= N_NODES ? N_NODES - 1 : v);
    int e = E[i]; e = (e < 0) ? 0 : (e >= M_EDGES ? M_EDGES - 1 : e);
    atomicAdd(&cntV[v], 1);
    atomicAdd(&cntE[e], 1);
  }
}

// ---- multi-block scan, both segments in one grid; also emits invDE/invSqrtD ----
__global__ __launch_bounds__(256) void scan1_kernel(const int* __restrict__ cntV, const int* __restrict__ cntE,
                                                    int* __restrict__ rowptrV, int* __restrict__ rowptrE,
                                                    int* __restrict__ blockSums,
                                                    float* __restrict__ invSqrtD,
                                                    float* __restrict__ invDE) {
  __shared__ int sm[256];
  const int b = blockIdx.x;
  const int tid = threadIdx.x;
  const bool isV = b < VBLK;
  const int n = isV ? N_NODES : M_EDGES;
  const int i = (isV ? b : b - VBLK) * 256 + tid;
  const int* cnt = isV ? cntV : cntE;
  int x = (i < n) ? cnt[i] : 0;
  if (i < n) {
    if (isV) invSqrtD[i] = 1.0f / sqrtf((float)x);
    else     invDE[i] = 1.0f / (float)x;
  }
  sm[tid] = x;
  __syncthreads();
#pragma unroll
  for (int off = 1; off < 256; off <<= 1) {
    int t = (tid >= off) ? sm[tid - off] : 0;
    __syncthreads();
    sm[tid] += t;
    __syncthreads();
  }
  int inc = sm[tid];
  int* rp = isV ? rowptrV : rowptrE;
  if (i < n) rp[i] = inc - x;
  if (tid == 255) blockSums[b] = inc;
}

__global__ __launch_bounds__(256) void scan2_kernel(int* __restrict__ blockSums) {
  __shared__ int sm[256];
  const int tid = threadIdx.x;
  int x = (tid < SBLK) ? blockSums[tid] : 0;
  sm[tid] = x;
  __syncthreads();
  const int segStart = (tid < VBLK) ? 0 : VBLK;
#pragma unroll
  for (int off = 1; off < 256; off <<= 1) {
    int t = (tid >= off && (tid - off) >= segStart) ? sm[tid - off] : 0;
    __syncthreads();
    sm[tid] += t;
    __syncthreads();
  }
  if (tid < SBLK) blockSums[tid] = sm[tid] - x;
}

__global__ __launch_bounds__(256) void scan3_kernel(int* __restrict__ cntV, int* __restrict__ cntE,
                                                    int* __restrict__ rowptrV, int* __restrict__ rowptrE,
                                                    const int* __restrict__ blockSums) {
  const int b = blockIdx.x;
  const int tid = threadIdx.x;
  const bool isV = b < VBLK;
  const int n = isV ? N_NODES : M_EDGES;
  const int i = (isV ? b : b - VBLK) * 256 + tid;
  int* rp = isV ? rowptrV : rowptrE;
  int* cur = isV ? cntV : cntE;
  if (i < n) {
    int val = rp[i] + blockSums[b];
    rp[i] = val;
    cur[i] = val;
  }
  if (b == 0 && tid == 0) { rowptrV[N_NODES] = NNZ_TOT; rowptrE[M_EDGES] = NNZ_TOT; }
}

__global__ __launch_bounds__(256) void fill_kernel(const int* __restrict__ V, const int* __restrict__ E,
                                                   int* __restrict__ curV, int* __restrict__ curE,
                                                   int* __restrict__ colE, int* __restrict__ colV) {
  int i = blockIdx.x * 256 + threadIdx.x;
  if (i < NNZ_TOT) {
    int v = V[i]; v = (v < 0) ? 0 : (v >= N_NODES ? N_NODES - 1 : v);
    int e = E[i]; e = (e < 0) ? 0 : (e >= M_EDGES ? M_EDGES - 1 : e);
    int p = atomicAdd(&curV[v], 1);
    colE[p] = e;
    int q = atomicAdd(&curE[e], 1);
    colV[q] = v;
  }
}

__global__ __launch_bounds__(256) void node_stats_kernel(const int* __restrict__ rowptrV,
                                                         const int* __restrict__ colE,
                                                         const float* __restrict__ invDE,
                                                         float* __restrict__ rv) {
  int v = blockIdx.x * 256 + threadIdx.x;
  if (v < N_NODES) {
    int b = rowptrV[v], e = rowptrV[v + 1];
    float r = 0.0f;
    for (int j = b; j < e; ++j) r += invDE[colE[j]];
    rv[v] = r;
  }
}

// one-time merged weight convert: W1 -> W1t [256][128] fp16; W2 -> W2t [48][256] fp16 (zero-pad 40..47)
__global__ __launch_bounds__(256) void wcvt_kernel(const float* __restrict__ W1, const float* __restrict__ W2,
                                                   __half* __restrict__ W1t, __half* __restrict__ W2t) {
  int i = blockIdx.x * 256 + threadIdx.x;
  if (i < DF * HID) {
    int k = i >> 8, n = i & 255;
    W1t[n * DF + k] = __float2half(W1[i]);
  } else {
    int j = i - DF * HID;                    // 0 .. 48*HID-1
    if (j < 48 * HID) {
      int n = j >> 8, k = j & 255;
      W2t[n * HID + k] = (n < NOUT) ? __float2half(W2[k * NOUT + n]) : __float2half(0.f);
    }
  }
}

// ------------------------------------------------------------- phi0: Bh0 = fp16(X*isd), Xh = fp16(X), phi partial
__global__ __launch_bounds__(256) void phi0_kernel(const float* __restrict__ X,
                                                   const float* __restrict__ invSqrtD,
                                                   const float* __restrict__ rv,
                                                   __half2* __restrict__ Bh,
                                                   __half2* __restrict__ Xh,
                                                   float* __restrict__ slot0) {
  __shared__ float red[4];
  int w = threadIdx.x >> 6;
  int v = (blockIdx.x << 2) + w;
  v = __builtin_amdgcn_readfirstlane(v);
  int lane = threadIdx.x & 63;
  float isd = invSqrtD[v];
  float2 xv = *(const float2*)(X + (size_t)v * DF + lane * 2);
  float bx = xv.x * isd, by = xv.y * isd;
  Bh[(size_t)v * 64 + lane] = __floats2half2_rn(bx, by);
  Xh[(size_t)v * 64 + lane] = __floats2half2_rn(xv.x, xv.y);
  float q = bx * bx + by * by;
#pragma unroll
  for (int off = 32; off > 0; off >>= 1) q += __shfl_down(q, off, 64);
  if (lane == 0) red[w] = q * rv[v];
  __syncthreads();
  if (threadIdx.x == 0)
    atomicAdd(&slot0[blockIdx.x & 63], red[0] + red[1] + red[2] + red[3]);
}

// ------------------------------------------------------------- V2E pass (one edge per wave)
// batches of 8 gathers, each PREDICATED on row validity: masked lanes fetch nothing.
__global__ __launch_bounds__(256) void v2e_kernel(const __half2* __restrict__ Bh, __half2* __restrict__ Peh,
                                                  const int* __restrict__ rowptrE,
                                                  const int* __restrict__ colV,
                                                  const float* __restrict__ invDE) {
  const int tid = threadIdx.x;
  const int lane = tid & 63;
  const int grp = lane >> 4;
  const int sub = lane & 15;
  const int e = blockIdx.x * 4 + (tid >> 6);   // grid 2500*4 = 10000 exact
  const int beg = rowptrE[e], end = rowptrE[e + 1];
  const int cnt = end - beg;

  float acc[8];
#pragma unroll
  for (int i = 0; i < 8; ++i) acc[i] = 0.f;
  const char* Bb = (const char*)Bh;

  for (int c0 = 0; c0 < cnt; c0 += 64) {
    int li = c0 + lane;
    int idx = colV[beg + (li < cnt ? li : cnt - 1)];
#pragma unroll 1
    for (int half = 0; half < 2; ++half) {
      int base0 = c0 + half * 32;
      if (base0 >= cnt) break;               // wave-uniform
      float4 r[8];
      bool ok[8];
#pragma unroll
      for (int u = 0; u < 8; ++u) {          // issue 8 predicated gathers back-to-back
        ok[u] = (base0 + u * 4 + grp) < cnt;
        int m = __shfl(idx, (half * 8 + u) * 4 + grp, 64);
        if (ok[u]) r[u] = *(const float4*)(Bb + ((size_t)m << 8) + (sub << 4));
      }
#pragma unroll
      for (int u = 0; u < 8; ++u) {
        if (ok[u]) {
          const __half2* h = (const __half2*)&r[u];
          float2 a0 = __half22float2(h[0]);
          float2 a1 = __half22float2(h[1]);
          float2 a2 = __half22float2(h[2]);
          float2 a3 = __half22float2(h[3]);
          acc[0] += a0.x * a0.x; acc[1] += a0.y * a0.y;
          acc[2] += a1.x * a1.x; acc[3] += a1.y * a1.y;
          acc[4] += a2.x * a2.x; acc[5] += a2.y * a2.y;
          acc[6] += a3.x * a3.x; acc[7] += a3.y * a3.y;
        }
      }
    }
  }
#pragma unroll
  for (int i = 0; i < 8; ++i) {
    acc[i] += __shfl_xor(acc[i], 16, 64);
    acc[i] += __shfl_xor(acc[i], 32, 64);
  }
  if (grp == 0) {
    float de = invDE[e];
    __half2 o[4];
#pragma unroll
    for (int i = 0; i < 4; ++i)
      o[i] = __floats2half2_rn(sqrtf(acc[2 * i] * de), sqrtf(acc[2 * i + 1] * de));
    *(float4*)((char*)Peh + ((size_t)e << 8) + (sub << 4)) = *(const float4*)o;
  }
}

// ------------------------------------------------------------- E2V (4 nodes per wave) + G + phi
// 16 rows per index load; all gathers PREDICATED -> traffic = valid rows only.
__global__ __launch_bounds__(256) void e2v_kernel(const __half2* __restrict__ Peh,
                                                  const __half2* __restrict__ Xh,
                                                  __half2* __restrict__ Bh,
                                                  const int* __restrict__ rowptrV,
                                                  const int* __restrict__ colE,
                                                  const float* __restrict__ invSqrtD,
                                                  const float* __restrict__ rv,
                                                  const float* __restrict__ slot0,
                                                  const float* __restrict__ slotPrev,
                                                  float* __restrict__ slotOut,
                                                  int isLast) {
  __shared__ float red[16];
  const int tid = threadIdx.x;
  const int lane = tid & 63;
  const int grp = lane >> 4;
  const int sub = lane & 15;
  const int wv = tid >> 6;
  const int v = blockIdx.x * 16 + wv * 4 + grp;   // grid 3125*16 = 50000 exact

  float p0 = slot0[lane];
  float pp = slotPrev[lane];
#pragma unroll
  for (int off = 32; off > 0; off >>= 1) {
    p0 += __shfl_xor(p0, off, 64);
    pp += __shfl_xor(pp, off, 64);
  }
  float s0 = 1.0f / (2.0f * sqrtf(p0));
  float sp = 1.0f / (2.0f * sqrtf(pp));

  const int beg = rowptrV[v], end = rowptrV[v + 1];
  const int cnt = end - beg;
  int cmax = cnt;
  cmax = max(cmax, __shfl_xor(cmax, 16, 64));
  cmax = max(cmax, __shfl_xor(cmax, 32, 64));

  float acc[8];
#pragma unroll
  for (int i = 0; i < 8; ++i) acc[i] = 0.f;
  const char* Pb = (const char*)Peh;

  for (int c0 = 0; c0 < cmax; c0 += 16) {
    int li = c0 + sub;
    int eidx = colE[beg + (li < cnt ? li : cnt - 1)];
    bool second = (c0 + 8 < cmax);            // wave-uniform
    float4 r[8], r2[8];
    bool ok[8], ok2[8];
#pragma unroll
    for (int u = 0; u < 8; ++u) {             // first 8 predicated gathers
      ok[u] = (c0 + u) < cnt;
      int m = __shfl(eidx, (grp << 4) | u, 64);
      if (ok[u]) r[u] = *(const float4*)(Pb + ((size_t)m << 8) + (sub << 4));
    }
    if (second) {
#pragma unroll
      for (int u = 0; u < 8; ++u) {           // next 8 (same index load)
        ok2[u] = (c0 + 8 + u) < cnt;
        int m = __shfl(eidx, (grp << 4) | (8 + u), 64);
        if (ok2[u]) r2[u] = *(const float4*)(Pb + ((size_t)m << 8) + (sub << 4));
      }
    }
#pragma unroll
    for (int u = 0; u < 8; ++u) {
      if (ok[u]) {
        const __half2* h = (const __half2*)&r[u];
        float2 a0 = __half22float2(h[0]);
        float2 a1 = __half22float2(h[1]);
        float2 a2 = __half22float2(h[2]);
        float2 a3 = __half22float2(h[3]);
        acc[0] += a0.x; acc[1] += a0.y;
        acc[2] += a1.x; acc[3] += a1.y;
        acc[4] += a2.x; acc[5] += a2.y;
        acc[6] += a3.x; acc[7] += a3.y;
      }
    }
    if (second) {
#pragma unroll
      for (int u = 0; u < 8; ++u) {
        if (ok2[u]) {
          const __half2* h = (const __half2*)&r2[u];
          float2 a0 = __half22float2(h[0]);
          float2 a1 = __half22float2(h[1]);
          float2 a2 = __half22float2(h[2]);
          float2 a3 = __half22float2(h[3]);
          acc[0] += a0.x; acc[1] += a0.y;
          acc[2] += a1.x; acc[3] += a1.y;
          acc[4] += a2.x; acc[5] += a2.y;
          acc[6] += a3.x; acc[7] += a3.y;
        }
      }
    }
  }

  float isd = invSqrtD[v];
  float c1 = 0.9f * sp * isd;
  float c0w = 0.1f * s0;
  float4 xr = *(const float4*)((const char*)Xh + ((size_t)v << 8) + (sub << 4));
  const __half2* xh = (const __half2*)&xr;
  float g[8];
#pragma unroll
  for (int i = 0; i < 4; ++i) {
    float2 xv = __half22float2(xh[i]);
    g[2 * i]     = c1 * acc[2 * i]     + c0w * xv.x;
    g[2 * i + 1] = c1 * acc[2 * i + 1] + c0w * xv.y;
  }
  float q = 0.f;
  __half2 o[4];
#pragma unroll
  for (int i = 0; i < 4; ++i) {
    float b0 = g[2 * i] * isd, b1 = g[2 * i + 1] * isd;
    q += b0 * b0 + b1 * b1;
    o[i] = isLast ? __floats2half2_rn(g[2 * i], g[2 * i + 1])
                  : __floats2half2_rn(b0, b1);
  }
  *(float4*)((char*)Bh + ((size_t)v << 8) + (sub << 4)) = *(const float4*)o;

#pragma unroll
  for (int off = 8; off > 0; off >>= 1) q += __shfl_xor(q, off, 64);
  if (sub == 0) red[wv * 4 + grp] = q * rv[v];
  __syncthreads();
  if (tid == 0) {
    float t = 0.f;
#pragma unroll
    for (int i = 0; i < 16; ++i) t += red[i];
    atomicAdd(&slotOut[blockIdx.x & 63], t);
  }
}

// ------------------------------------------------------------- fused decoder (MFMA both GEMMs)
// 256 threads = 4 waves, 32 nodes/block. GEMM2 on waves 0..1 (round-11 best).
__global__ __launch_bounds__(256) void decoder_kernel(const __half2* __restrict__ Gh,
                                                      const __half* __restrict__ W1t,
                                                      const __half* __restrict__ W2t,
                                                      const float* __restrict__ slot10,
                                                      const float* __restrict__ b1,
                                                      const float* __restrict__ gam, const float* __restrict__ bet,
                                                      const float* __restrict__ b2,
                                                      float* __restrict__ out) {
  __shared__ __half h16[32 * 264];         // 16,896 B
  __shared__ float lnbuf[32 * 4];

  const int tid = threadIdx.x;
  const int lane = tid & 63;
  const int w = tid >> 6;                  // wave 0..3
  const int quad = lane >> 4;
  const int col = lane & 15;
  const int m0 = (w >> 1) * 16;
  const int nh0 = (w & 1) * 128;
  const int node0 = blockIdx.x * 32;

  float ps = slot10[lane];
#pragma unroll
  for (int off = 32; off > 0; off >>= 1) ps += __shfl_xor(ps, off, 64);
  const float s = 1.0f / (2.0f * sqrtf(ps));   // 1/phi(G10)

  f32x4 acc[8];
#pragma unroll
  for (int t = 0; t < 8; ++t) acc[t] = (f32x4){0.f, 0.f, 0.f, 0.f};

  int an = node0 + m0 + col;
  if (an > N_NODES - 1) an = N_NODES - 1;
  const char* Gb = (const char*)Gh;
  const char* Wb = (const char*)W1t;

#pragma unroll
  for (int kb = 0; kb < 4; ++kb) {
    fp16x8 af = *(const fp16x8*)(Gb + (size_t)an * 256 + kb * 64 + quad * 16);
#pragma unroll
    for (int t = 0; t < 8; ++t) {
      int n = nh0 + t * 16 + col;
      fp16x8 bf = *(const fp16x8*)(Wb + (size_t)n * 256 + kb * 64 + quad * 16);
      acc[t] = __builtin_amdgcn_mfma_f32_16x16x32_f16(af, bf, acc[t], 0, 0, 0);
    }
  }

  float hv[8][4];
  float s1[4] = {0.f, 0.f, 0.f, 0.f}, s2[4] = {0.f, 0.f, 0.f, 0.f};
#pragma unroll
  for (int t = 0; t < 8; ++t) {
    float bb = b1[nh0 + t * 16 + col];
#pragma unroll
    for (int r = 0; r < 4; ++r) {
      float h = s * acc[t][r] + bb;
      hv[t][r] = h;
      s1[r] += h;
      s2[r] += h * h;
    }
  }
#pragma unroll
  for (int off = 8; off > 0; off >>= 1) {
#pragma unroll
    for (int r = 0; r < 4; ++r) {
      s1[r] += __shfl_xor(s1[r], off, 64);
      s2[r] += __shfl_xor(s2[r], off, 64);
    }
  }
  if (col == 0) {
#pragma unroll
    for (int r = 0; r < 4; ++r) {
      int nd = m0 + quad * 4 + r;
      lnbuf[nd * 4 + (w & 1) * 2 + 0] = s1[r];
      lnbuf[nd * 4 + (w & 1) * 2 + 1] = s2[r];
    }
  }
  __syncthreads();
  float mu[4], rs[4];
#pragma unroll
  for (int r = 0; r < 4; ++r) {
    int nd = m0 + quad * 4 + r;
    float t1 = lnbuf[nd * 4 + 0] + lnbuf[nd * 4 + 2];
    float t2 = lnbuf[nd * 4 + 1] + lnbuf[nd * 4 + 3];
    float m = t1 * (1.0f / 256.0f);
    float var = t2 * (1.0f / 256.0f) - m * m;
    mu[r] = m;
    rs[r] = rsqrtf(var + 1e-5f);
  }
#pragma unroll
  for (int t = 0; t < 8; ++t) {
    int hid = nh0 + t * 16 + col;
    float ga = gam[hid], be = bet[hid];
#pragma unroll
    for (int r = 0; r < 4; ++r) {
      float h = fmaxf(0.0f, (hv[t][r] - mu[r]) * rs[r] * ga + be);
      h16[(m0 + quad * 4 + r) * 264 + hid] = __float2half(h);
    }
  }
  __syncthreads();

  // GEMM2 (waves 0..1): 16 nodes x 48 outs per wave, K=256
  if (w < 2) {
    const int m0b = w * 16;
    f32x4 c[3];
#pragma unroll
    for (int nt = 0; nt < 3; ++nt) c[nt] = (f32x4){0.f, 0.f, 0.f, 0.f};
#pragma unroll
    for (int kb = 0; kb < 8; ++kb) {
      fp16x8 af = *(const fp16x8*)&h16[(m0b + col) * 264 + kb * 32 + quad * 8];
#pragma unroll
      for (int nt = 0; nt < 3; ++nt) {
        fp16x8 bf = *(const fp16x8*)(W2t + (nt * 16 + col) * HID + kb * 32 + quad * 8);
        c[nt] = __builtin_amdgcn_mfma_f32_16x16x32_f16(af, bf, c[nt], 0, 0, 0);
      }
    }
#pragma unroll
    for (int nt = 0; nt < 3; ++nt) {
      int oc = nt * 16 + col;
      if (oc < NOUT) {
        float bb = b2[oc];
#pragma unroll
        for (int r = 0; r < 4; ++r) {
          int node = node0 + m0b + quad * 4 + r;
          if (node < N_NODES) out[(size_t)node * NOUT + oc] = c[nt][r] + bb;
        }
      }
    }
  }
}

// ---------------------------------------------------------------- launch
extern "C" void kernel_launch(void* const* d_in, const int* in_sizes, int n_in,
                              void* d_out, int out_size, void* d_ws, size_t ws_size,
                              hipStream_t stream) {
  (void)in_sizes; (void)n_in; (void)out_size; (void)ws_size;
  const float* x = (const float*)d_in[0];
  const int* he = (const int*)d_in[1];
  const int* V = he;
  const int* E = he + NNZ_TOT;
  const float* W1 = (const float*)d_in[2];
  const float* b1 = (const float*)d_in[3];
  const float* gam = (const float*)d_in[4];
  const float* bet = (const float*)d_in[5];
  const float* W2 = (const float*)d_in[6];
  const float* b2 = (const float*)d_in[7];
  float* out = (float*)d_out;

  // Peh (2.56 MB fp16) lives in d_out (8 MB): dead before decoder (sole d_out writer) runs.
  __half2* Peh = (__half2*)d_out;

  char* p = (char*)d_ws;
  auto nextp = [&](size_t bytes) -> char* {
    char* r = p;
    p += (bytes + 255) & ~(size_t)255;
    return r;
  };
  int* cntV      = (int*)nextp((size_t)(N_NODES + M_EDGES) * 4 + 11 * 64 * 4);
  int* cntE      = cntV + N_NODES;
  float* phis    = (float*)(cntE + M_EDGES);     // [11][64] striped phi partials
  int* rowptrV   = (int*)nextp((size_t)(N_NODES + 1) * 4);
  int* rowptrE   = (int*)nextp((size_t)(M_EDGES + 1) * 4);
  int* blockSums = (int*)nextp((size_t)SBLK * 4);
  int* colE      = (int*)nextp((size_t)NNZ_TOT * 4);
  int* colV      = (int*)nextp((size_t)NNZ_TOT * 4);
  float* invSqrtD= (float*)nextp((size_t)N_NODES * 4);
  float* rv      = (float*)nextp((size_t)N_NODES * 4);
  float* invDE   = (float*)nextp((size_t)M_EDGES * 4);
  __half* W1t    = (__half*)nextp((size_t)DF * HID * 2);        // fp16 W1^T, 64 KB
  __half* W2t    = (__half*)nextp((size_t)48 * HID * 2);        // fp16 W2^T padded, 24.6 KB
  __half2* Bh    = (__half2*)nextp((size_t)N_NODES * DF * 2);   // fp16 iterate, 12.8 MB
  __half2* Xh    = (__half2*)nextp((size_t)N_NODES * DF * 2);   // fp16 anchor, 12.8 MB

  const int NBLK_NNZ = (NNZ_TOT + 255) / 256;

  hipMemsetAsync(cntV, 0, (size_t)(N_NODES + M_EDGES) * 4 + 11 * 64 * 4, stream);
  count_kernel<<<NBLK_NNZ, 256, 0, stream>>>(V, E, cntV, cntE);
  scan1_kernel<<<SBLK, 256, 0, stream>>>(cntV, cntE, rowptrV, rowptrE, blockSums, invSqrtD, invDE);
  scan2_kernel<<<1, 256, 0, stream>>>(blockSums);
  scan3_kernel<<<SBLK, 256, 0, stream>>>(cntV, cntE, rowptrV, rowptrE, blockSums);
  fill_kernel<<<NBLK_NNZ, 256, 0, stream>>>(V, E, cntV, cntE, colE, colV);
  node_stats_kernel<<<(N_NODES + 255) / 256, 256, 0, stream>>>(rowptrV, colE, invDE, rv);
  wcvt_kernel<<<(DF * HID + 48 * HID + 255) / 256, 256, 0, stream>>>(W1, W2, W1t, W2t);
  phi0_kernel<<<N_NODES / 4, 256, 0, stream>>>(x, invSqrtD, rv, Bh, Xh, phis);

  for (int k = 1; k <= 10; ++k) {
    v2e_kernel<<<M_EDGES / 4, 256, 0, stream>>>(Bh, Peh, rowptrE, colV, invDE);
    e2v_kernel<<<N_NODES / 16, 256, 0, stream>>>(Peh, Xh, Bh, rowptrV, colE, invSqrtD, rv,
                                                 phis, phis + (size_t)(k - 1) * 64,
                                                 phis + (size_t)k * 64, (k == 10) ? 1 : 0);
  }

  decoder_kernel<<<(N_NODES + 31) / 32, 256, 0, stream>>>(Bh, W1t, W2t, phis + 640,
                                                          b1, gam, bet, b2, out);
}